// Round 5
// baseline (607.030 us; speedup 1.0000x reference)
//
#include <hip/hip_runtime.h>
#include <hip/hip_bf16.h>

typedef __bf16 bf16_t;
typedef __bf16 bf16x8 __attribute__((ext_vector_type(8)));
typedef __bf16 bf16x4 __attribute__((ext_vector_type(4)));
typedef float  f32x4  __attribute__((ext_vector_type(4)));

#define NB 8
#define CD 2048
#define BD 2048
#define LD 2048
#define BK 64
#define NT (LD / BK)
#define NP (NT / 2)

#define BAR()    asm volatile("s_barrier" ::: "memory")
#define WAITL0() asm volatile("s_waitcnt lgkmcnt(0)" ::: "memory")
#define WAITL8() asm volatile("s_waitcnt lgkmcnt(8)" ::: "memory")
#define WAITV(n) asm volatile("s_waitcnt vmcnt(" #n ")" ::: "memory")

// ---------------- X [N,C,B] f32 -> XbT [N,B,C] bf16 (transpose + convert) ----------------
__global__ void k_transpose_x(const float* __restrict__ X, bf16_t* __restrict__ XbT) {
    __shared__ bf16_t tile[64][66];
    const int t = threadIdx.x;
    const int b0 = blockIdx.x * 64, c0 = blockIdx.y * 64, n = blockIdx.z;
    const float* Xn = X + (size_t)n * CD * BD;
    bf16_t* Tn = XbT + (size_t)n * BD * CD;
    const int cl = t & 63, rw = t >> 6;
#pragma unroll
    for (int r = 0; r < 16; ++r) {
        int row = r * 4 + rw;
        tile[row][cl] = (bf16_t)Xn[(size_t)(c0 + row) * BD + b0 + cl];
    }
    __syncthreads();
#pragma unroll
    for (int r = 0; r < 16; ++r) {
        int row = r * 4 + rw;
        Tn[(size_t)(b0 + row) * CD + c0 + cl] = tile[cl][row];
    }
}

// ---------------- Wk/Wq f32 -> bf16 ----------------
__global__ void k_convert_w(const float* __restrict__ Wk, const float* __restrict__ Wq,
                            bf16_t* __restrict__ Wkb, bf16_t* __restrict__ Wqb) {
    const size_t i = ((size_t)blockIdx.x * 256 + threadIdx.x) * 4;
    const float* src = blockIdx.y ? Wq : Wk;
    bf16_t* dst = blockIdx.y ? Wqb : Wkb;
    float4 v = *(const float4*)(src + i);
    bf16x4 o;
    o[0] = (bf16_t)v.x; o[1] = (bf16_t)v.y; o[2] = (bf16_t)v.z; o[3] = (bf16_t)v.w;
    *(bf16x4*)(dst + i) = o;
}

// ============ 256x256 NT GEMM — m201 8-phase template, exact transcription ============
// C[M,N] = A[M,K](rm) * B[N,K](rm)^T. 8 waves; per phase all 8 waves compute ONE
// block-level 128x128 C-quadrant (wave sub-tile 64x32, 16 MFMA). 2 K-tiles/iter,
// 8 phases/iter, reads/phase {12,4,8,0} (A-frags reused in regs across 2 phases),
// ONE half-tile staged per phase in region-death order, vmcnt(6) at P4/P8 only.

__device__ __forceinline__ void gll16(const bf16_t* g, bf16_t* l) {
    __builtin_amdgcn_global_load_lds((const __attribute__((address_space(1))) void*)g,
                                     (__attribute__((address_space(3))) void*)l, 16, 0, 0);
}

__device__ __forceinline__ void stage_half(const bf16_t* gsrc, bf16_t* ldsh, int w, int l) {
    const int rr = l >> 3;
    const int ce = ((l & 7) ^ rr) * 8;  // pre-swizzled source chunk (involution)
#pragma unroll
    for (int i = 0; i < 2; ++i) {
        const bf16_t* g = gsrc + (size_t)(i * 64 + w * 8 + rr) * LD + ce;
        gll16(g, ldsh + i * 4096 + w * 512);
    }
}

__device__ __forceinline__ bf16x8 lds_frag(const bf16_t* hbase, int row16, int lr, int st, int ks, int swz) {
    const int r = row16 + lr;
    const int ce = (st * 32 + ks * 8) ^ swz;
    return *(const bf16x8*)(hbase + r * 64 + ce);
}

template <int EPI>  // 0: f32 store; 1: +bias[row], bf16 store
__global__ __launch_bounds__(512, 2) void k_gemm256(const bf16_t* __restrict__ Aall, size_t sA,
                                                    const bf16_t* __restrict__ Ball, size_t sB,
                                                    void* __restrict__ Call, size_t sC,
                                                    const float* __restrict__ bias) {
    __shared__ alignas(16) bf16_t As[2][2][128 * 64];  // [slot][half]; slot0=even tile, slot1=odd
    __shared__ alignas(16) bf16_t Bs[2][2][128 * 64];
    const int tid = threadIdx.x;
    const int lane = tid & 63, wave = tid >> 6;
    const int wm = wave >> 2, wn = wave & 3;           // wave covers rows wm*64, cols wn*32 of each quadrant
    const int lr = lane & 15, ks = lane >> 4;
    const int swz = (lr & 7) << 3;

    const int bid = blockIdx.x;
    const int lin = (bid & 7) * 64 + (bid >> 3);       // XCD-aware remap (512 % 8 == 0: bijective)
    const int z = lin >> 6, rem = lin & 63, bm = rem >> 3, bn = rem & 7;
    const int m0 = bm * 256, n0 = bn * 256;

    const bf16_t* Ab = Aall + sA * z + (size_t)m0 * LD;
    const bf16_t* Bb = Ball + sB * z + (size_t)n0 * LD;

    // prologue: t0 {A0,B0,A1,B1}; vmcnt(4); t1 {A0,B0,B1}; vmcnt(6)  (t1.A1 staged at P1)
    stage_half(Ab,                 &As[0][0][0], wave, lane);
    stage_half(Bb,                 &Bs[0][0][0], wave, lane);
    stage_half(Ab + 128 * LD,      &As[0][1][0], wave, lane);
    stage_half(Bb + 128 * LD,      &Bs[0][1][0], wave, lane);
    WAITV(4);
    stage_half(Ab + BK,            &As[1][0][0], wave, lane);
    stage_half(Bb + BK,            &Bs[1][0][0], wave, lane);
    stage_half(Bb + 128 * LD + BK, &Bs[1][1][0], wave, lane);
    WAITV(6);
    BAR();

    f32x4 acc[2][2][4][2] = {};       // [mh][nh][mi][ni]
    bf16x8 afr[4][2], bf0[2][2], bf1[2][2];

    auto RD_A = [&](int slot, int half) {
#pragma unroll
        for (int mi = 0; mi < 4; ++mi)
#pragma unroll
            for (int st = 0; st < 2; ++st)
                afr[mi][st] = lds_frag(&As[slot][half][0], wm * 64 + mi * 16, lr, st, ks, swz);
    };
    auto RD_B = [&](bf16x8 (&dst)[2][2], int slot, int half) {
#pragma unroll
        for (int ni = 0; ni < 2; ++ni)
#pragma unroll
            for (int st = 0; st < 2; ++st)
                dst[ni][st] = lds_frag(&Bs[slot][half][0], wn * 32 + ni * 16, lr, st, ks, swz);
    };
    auto MFMA_Q = [&](int mh, int nh, bf16x8 (&bsrc)[2][2]) {
        __builtin_amdgcn_s_setprio(1);
#pragma unroll
        for (int mi = 0; mi < 4; ++mi)
#pragma unroll
            for (int ni = 0; ni < 2; ++ni)
#pragma unroll
                for (int st = 0; st < 2; ++st)
                    acc[mh][nh][mi][ni] = __builtin_amdgcn_mfma_f32_16x16x32_bf16(
                        afr[mi][st], bsrc[ni][st], acc[mh][nh][mi][ni], 0, 0, 0);
        __builtin_amdgcn_s_setprio(0);
    };

    for (int tp = 0; tp < NP; ++tp) {
        const int u = 2 * tp, v = u + 1;
        const int w = (u + 2 < NT) ? u + 2 : NT - 1;  // tail clamps are region-safe dummies
        const int x = (v + 2 < NT) ? v + 2 : NT - 1;

        // P1: reads u.A0(8)+u.B0(4); stage v.A1 -> s1A1 (dead since prev P7)
        RD_A(0, 0); RD_B(bf0, 0, 0);
        stage_half(Ab + 128 * LD + v * BK, &As[1][1][0], wave, lane);
        WAITL8();
        BAR(); WAITL0();
        MFMA_Q(0, 0, bf0);
        BAR();

        // P2: reads u.B1(4); stage w.A0 -> s0A0 (dead after P1)
        RD_B(bf1, 0, 1);
        stage_half(Ab + w * BK, &As[0][0][0], wave, lane);
        BAR(); WAITL0();
        MFMA_Q(0, 1, bf1);
        BAR();

        // P3: reads u.A1(8); stage w.B0 -> s0B0 (dead after P1)
        RD_A(0, 1);
        stage_half(Bb + w * BK, &Bs[0][0][0], wave, lane);
        BAR(); WAITL0();
        MFMA_Q(1, 0, bf0);
        BAR();

        // P4: no reads; stage w.B1 -> s0B1 (dead after P2); vmcnt(6) retires ALL of v
        stage_half(Bb + 128 * LD + w * BK, &Bs[0][1][0], wave, lane);
        WAITV(6);
        BAR();
        MFMA_Q(1, 1, bf1);
        BAR();

        // P5: reads v.A0(8)+v.B0(4); stage w.A1 -> s0A1 (dead after P3)
        RD_A(1, 0); RD_B(bf0, 1, 0);
        stage_half(Ab + 128 * LD + w * BK, &As[0][1][0], wave, lane);
        WAITL8();
        BAR(); WAITL0();
        MFMA_Q(0, 0, bf0);
        BAR();

        // P6: reads v.B1(4); stage x.A0 -> s1A0 (dead after P5)
        RD_B(bf1, 1, 1);
        stage_half(Ab + x * BK, &As[1][0][0], wave, lane);
        BAR(); WAITL0();
        MFMA_Q(0, 1, bf1);
        BAR();

        // P7: reads v.A1(8); stage x.B0 -> s1B0 (dead after P5)
        RD_A(1, 1);
        stage_half(Bb + x * BK, &Bs[1][0][0], wave, lane);
        BAR(); WAITL0();
        MFMA_Q(1, 0, bf0);
        BAR();

        // P8: no reads; stage x.B1 -> s1B1 (dead after P6); vmcnt(6) retires ALL of w
        stage_half(Bb + 128 * LD + x * BK, &Bs[1][1][0], wave, lane);
        WAITV(6);
        BAR();
        MFMA_Q(1, 1, bf1);
        BAR();
    }
    WAITV(0);  // drain tail dummy stages before exit

    // epilogue: row = m0 + mh*128 + wm*64 + mi*16 + ks*4 + j; col = n0 + nh*128 + wn*32 + ni*16 + lr
    const int rsub = ks * 4;
#pragma unroll
    for (int mh = 0; mh < 2; ++mh)
#pragma unroll
        for (int mi = 0; mi < 4; ++mi)
#pragma unroll
            for (int j = 0; j < 4; ++j) {
                const int r = m0 + mh * 128 + wm * 64 + mi * 16 + rsub + j;
                float bv = 0.f;
                if (EPI == 1) bv = bias[r];
#pragma unroll
                for (int nh = 0; nh < 2; ++nh)
#pragma unroll
                    for (int ni = 0; ni < 2; ++ni) {
                        const int c = n0 + nh * 128 + wn * 32 + ni * 16 + lr;
                        const float vv = acc[mh][nh][mi][ni][j] + bv;
                        if (EPI == 1) ((bf16_t*)Call)[sC * z + (size_t)r * LD + c] = (bf16_t)vv;
                        else          ((float*)Call)[sC * z + (size_t)r * LD + c] = vv;
                    }
            }
}

// ---------------- squared row norms of Kb/Qb (bf16 [N,C,B]) -> f32 [N,C] ----------------
__global__ void k_row_norm2(const bf16_t* __restrict__ Kb, const bf16_t* __restrict__ Qb,
                            float* __restrict__ DK2, float* __restrict__ DQ2) {
    const int row = blockIdx.x, n = blockIdx.y;
    const bf16_t* src = blockIdx.z ? Qb : Kb;
    float* dst = blockIdx.z ? DQ2 : DK2;
    const bf16_t* pr = src + ((size_t)n * CD + row) * BD + threadIdx.x * 8;
    bf16x8 v = *(const bf16x8*)pr;
    float s = 0.f;
#pragma unroll
    for (int e = 0; e < 8; ++e) { float x = (float)v[e]; s += x * x; }
#pragma unroll
    for (int off = 32; off; off >>= 1) s += __shfl_xor(s, off, 64);
    __shared__ float ws[4];
    if ((threadIdx.x & 63) == 0) ws[threadIdx.x >> 6] = s;
    __syncthreads();
    if (threadIdx.x == 0) dst[(size_t)n * CD + row] = ws[0] + ws[1] + ws[2] + ws[3];
}

// ------- per-row: scale by rsqrt(DQ2[i]*DK2[j]), softmax over i, write bf16 SMT[j,i] -------
__global__ void k_softmax_rows(const float* __restrict__ Yt, const float* __restrict__ DK2,
                               const float* __restrict__ DQ2, bf16_t* __restrict__ SMT) {
    const int j = blockIdx.x, n = blockIdx.y, t = threadIdx.x;
    const int lane = t & 63, wave = t >> 6;
    const float* y = Yt + ((size_t)n * CD + j) * CD;
    const float* q2 = DQ2 + (size_t)n * CD;
    const float dk2 = DK2[(size_t)n * CD + j];
    const int i0 = t * 8;

    float v[8];
    float4 a = *(const float4*)(y + i0);
    float4 b = *(const float4*)(y + i0 + 4);
    float4 qa = *(const float4*)(q2 + i0);
    float4 qb = *(const float4*)(q2 + i0 + 4);
    v[0] = a.x * rsqrtf(fmaxf(dk2 * qa.x, 1e-12f));
    v[1] = a.y * rsqrtf(fmaxf(dk2 * qa.y, 1e-12f));
    v[2] = a.z * rsqrtf(fmaxf(dk2 * qa.z, 1e-12f));
    v[3] = a.w * rsqrtf(fmaxf(dk2 * qa.w, 1e-12f));
    v[4] = b.x * rsqrtf(fmaxf(dk2 * qb.x, 1e-12f));
    v[5] = b.y * rsqrtf(fmaxf(dk2 * qb.y, 1e-12f));
    v[6] = b.z * rsqrtf(fmaxf(dk2 * qb.z, 1e-12f));
    v[7] = b.w * rsqrtf(fmaxf(dk2 * qb.w, 1e-12f));

    float m = v[0];
#pragma unroll
    for (int e = 1; e < 8; ++e) m = fmaxf(m, v[e]);
#pragma unroll
    for (int off = 32; off; off >>= 1) m = fmaxf(m, __shfl_xor(m, off, 64));
    __shared__ float redm[4], reds[4];
    if (lane == 0) redm[wave] = m;
    __syncthreads();
    m = fmaxf(fmaxf(redm[0], redm[1]), fmaxf(redm[2], redm[3]));

    float e8[8];
    float s = 0.f;
#pragma unroll
    for (int e = 0; e < 8; ++e) { e8[e] = __expf(v[e] - m); s += e8[e]; }
#pragma unroll
    for (int off = 32; off; off >>= 1) s += __shfl_xor(s, off, 64);
    if (lane == 0) reds[wave] = s;
    __syncthreads();
    s = reds[0] + reds[1] + reds[2] + reds[3];
    const float inv = 1.f / s;

    bf16x8 o;
#pragma unroll
    for (int e = 0; e < 8; ++e) o[e] = (bf16_t)(e8[e] * inv);
    *(bf16x8*)(SMT + ((size_t)n * CD + j) * CD + i0) = o;
}

extern "C" void kernel_launch(void* const* d_in, const int* in_sizes, int n_in,
                              void* d_out, int out_size, void* d_ws, size_t ws_size,
                              hipStream_t stream) {
    const float* X   = (const float*)d_in[0];
    const float* Wk  = (const float*)d_in[1];
    const float* Wq  = (const float*)d_in[2];
    const float* Wk0 = (const float*)d_in[3];
    const float* Wq0 = (const float*)d_in[4];
    float* Z = (float*)d_out;

    const size_t NCB = (size_t)NB * CD * BD;
    const size_t CC  = (size_t)CD * CD;
    const size_t NCC = (size_t)NB * CC;

    char* p = (char*)d_ws;
    bf16_t* XbT = (bf16_t*)p; p += NCB * 2;
    bf16_t* Wkb = (bf16_t*)p; p += CC * 2;
    bf16_t* Wqb = (bf16_t*)p; p += CC * 2;
    bf16_t* Kb  = (bf16_t*)p; p += NCB * 2;
    bf16_t* Qb  = (bf16_t*)p; p += NCB * 2;
    float*  DK2 = (float*)p;  p += (size_t)NB * CD * 4;
    float*  DQ2 = (float*)p;  p += (size_t)NB * CD * 4;
    float*  Yt  = (float*)p;  p += NCC * 4;
    bf16_t* SMT = Kb;  // Kb dead after Yt; reuse
    if ((size_t)(p - (char*)d_ws) > ws_size) return;

    dim3 blk(256);
    k_transpose_x<<<dim3(BD / 64, CD / 64, NB), blk, 0, stream>>>(X, XbT);
    k_convert_w<<<dim3(CC / 1024, 2), blk, 0, stream>>>(Wk, Wq, Wkb, Wqb);
    k_gemm256<1><<<512, 512, 0, stream>>>(Wkb, 0, XbT, (size_t)BD * CD, Kb, (size_t)CD * BD, Wk0);
    k_gemm256<1><<<512, 512, 0, stream>>>(Wqb, 0, XbT, (size_t)BD * CD, Qb, (size_t)CD * BD, Wq0);
    k_row_norm2<<<dim3(CD, NB, 2), blk, 0, stream>>>(Kb, Qb, DK2, DQ2);
    k_gemm256<0><<<512, 512, 0, stream>>>(Kb, (size_t)CD * BD, Qb, (size_t)CD * BD, Yt, CC, nullptr);
    k_softmax_rows<<<dim3(CD, NB), blk, 0, stream>>>(Yt, DK2, DQ2, SMT);
    k_gemm256<0><<<512, 512, 0, stream>>>(SMT, CC, XbT, (size_t)BD * CD, Z, (size_t)CD * BD, nullptr);
}

// Round 6
// 578.500 us; speedup vs baseline: 1.0493x; 1.0493x over previous
//
#include <hip/hip_runtime.h>
#include <hip/hip_bf16.h>

typedef __bf16 bf16_t;
typedef __bf16 bf16x8 __attribute__((ext_vector_type(8)));
typedef __bf16 bf16x4 __attribute__((ext_vector_type(4)));
typedef float  f32x4  __attribute__((ext_vector_type(4)));

#define NB 8
#define CD 2048
#define BD 2048
#define LD 2048
#define BK 64
#define NT (LD / BK)
#define NP (NT / 2)

#define BAR()     __builtin_amdgcn_s_barrier()
#define WAITL0()  asm volatile("s_waitcnt lgkmcnt(0)")
#define WAITL8()  asm volatile("s_waitcnt lgkmcnt(8)")
#define WAITV(n)  asm volatile("s_waitcnt vmcnt(" #n ")" ::: "memory")

// ---------------- X [N,C,B] f32 -> XbT [N,B,C] bf16 (transpose + convert) ----------------
__global__ void k_transpose_x(const float* __restrict__ X, bf16_t* __restrict__ XbT) {
    __shared__ bf16_t tile[64][66];
    const int t = threadIdx.x;
    const int b0 = blockIdx.x * 64, c0 = blockIdx.y * 64, n = blockIdx.z;
    const float* Xn = X + (size_t)n * CD * BD;
    bf16_t* Tn = XbT + (size_t)n * BD * CD;
    const int cl = t & 63, rw = t >> 6;
#pragma unroll
    for (int r = 0; r < 16; ++r) {
        int row = r * 4 + rw;
        tile[row][cl] = (bf16_t)Xn[(size_t)(c0 + row) * BD + b0 + cl];
    }
    __syncthreads();
#pragma unroll
    for (int r = 0; r < 16; ++r) {
        int row = r * 4 + rw;
        Tn[(size_t)(b0 + row) * CD + c0 + cl] = tile[cl][row];
    }
}

// ---------------- Wk/Wq f32 -> bf16 ----------------
__global__ void k_convert_w(const float* __restrict__ Wk, const float* __restrict__ Wq,
                            bf16_t* __restrict__ Wkb, bf16_t* __restrict__ Wqb) {
    const size_t i = ((size_t)blockIdx.x * 256 + threadIdx.x) * 4;
    const float* src = blockIdx.y ? Wq : Wk;
    bf16_t* dst = blockIdx.y ? Wqb : Wkb;
    float4 v = *(const float4*)(src + i);
    bf16x4 o;
    o[0] = (bf16_t)v.x; o[1] = (bf16_t)v.y; o[2] = (bf16_t)v.z; o[3] = (bf16_t)v.w;
    *(bf16x4*)(dst + i) = o;
}

// ============ 256x256 NT GEMM — m201 8-phase template, builtin barriers ============
// C[M,N] = A[M,K](rm) * B[N,K](rm)^T. 8 waves; per phase all 8 waves compute ONE
// block-level 128x128 C-quadrant (wave sub-tile 64x32, 16 MFMA). 2 K-tiles/iter,
// 8 phases/iter, reads/phase {12,4,8,0}; ONE half-tile staged per phase in
// region-death order; vmcnt(6)+memory-anchor at P4/P8 only. All other syncs are
// builtin barriers / clobber-free waitcnt so the scheduler can pipeline across phases.

__device__ __forceinline__ void gll16(const bf16_t* g, bf16_t* l) {
    __builtin_amdgcn_global_load_lds((const __attribute__((address_space(1))) void*)g,
                                     (__attribute__((address_space(3))) void*)l, 16, 0, 0);
}

__device__ __forceinline__ void stage_half(const bf16_t* gsrc, bf16_t* ldsh, int w, int l) {
    const int rr = l >> 3;
    const int ce = ((l & 7) ^ rr) * 8;  // pre-swizzled source chunk (involution)
#pragma unroll
    for (int i = 0; i < 2; ++i) {
        const bf16_t* g = gsrc + (size_t)(i * 64 + w * 8 + rr) * LD + ce;
        gll16(g, ldsh + i * 4096 + w * 512);
    }
}

__device__ __forceinline__ bf16x8 lds_frag(const bf16_t* hbase, int row16, int lr, int st, int ks, int swz) {
    const int r = row16 + lr;
    const int ce = (st * 32 + ks * 8) ^ swz;
    return *(const bf16x8*)(hbase + r * 64 + ce);
}

template <int EPI>  // 0: f32 store; 1: +bias[row] bf16 store; 2: plain bf16 store
__global__ __launch_bounds__(512, 2) void k_gemm256(const bf16_t* __restrict__ Aall, size_t sA,
                                                    const bf16_t* __restrict__ Ball, size_t sB,
                                                    void* __restrict__ Call, size_t sC,
                                                    const float* __restrict__ bias) {
    __shared__ alignas(16) bf16_t As[2][2][128 * 64];  // [slot][half]
    __shared__ alignas(16) bf16_t Bs[2][2][128 * 64];
    const int tid = threadIdx.x;
    const int lane = tid & 63, wave = tid >> 6;
    const int wm = wave >> 2, wn = wave & 3;
    const int lr = lane & 15, ks = lane >> 4;
    const int swz = (lr & 7) << 3;

    const int bid = blockIdx.x;
    const int lin = (bid & 7) * 64 + (bid >> 3);       // XCD-aware remap (512 % 8 == 0: bijective)
    const int z = lin >> 6, rem = lin & 63, bm = rem >> 3, bn = rem & 7;
    const int m0 = bm * 256, n0 = bn * 256;

    const bf16_t* Ab = Aall + sA * z + (size_t)m0 * LD;
    const bf16_t* Bb = Ball + sB * z + (size_t)n0 * LD;

    // prologue: t0 {A0,B0,A1,B1}; vmcnt(4); t1 {A0,B0,B1}; vmcnt(6)  (t1.A1 staged at P1)
    stage_half(Ab,                 &As[0][0][0], wave, lane);
    stage_half(Bb,                 &Bs[0][0][0], wave, lane);
    stage_half(Ab + 128 * LD,      &As[0][1][0], wave, lane);
    stage_half(Bb + 128 * LD,      &Bs[0][1][0], wave, lane);
    WAITV(4);
    stage_half(Ab + BK,            &As[1][0][0], wave, lane);
    stage_half(Bb + BK,            &Bs[1][0][0], wave, lane);
    stage_half(Bb + 128 * LD + BK, &Bs[1][1][0], wave, lane);
    WAITV(6);
    BAR();

    f32x4 acc[2][2][4][2] = {};       // [mh][nh][mi][ni]
    bf16x8 afr[4][2], bf0[2][2], bf1[2][2];

    auto RD_A = [&](int slot, int half) {
#pragma unroll
        for (int mi = 0; mi < 4; ++mi)
#pragma unroll
            for (int st = 0; st < 2; ++st)
                afr[mi][st] = lds_frag(&As[slot][half][0], wm * 64 + mi * 16, lr, st, ks, swz);
    };
    auto RD_B = [&](bf16x8 (&dst)[2][2], int slot, int half) {
#pragma unroll
        for (int ni = 0; ni < 2; ++ni)
#pragma unroll
            for (int st = 0; st < 2; ++st)
                dst[ni][st] = lds_frag(&Bs[slot][half][0], wn * 32 + ni * 16, lr, st, ks, swz);
    };
    auto MFMA_Q = [&](int mh, int nh, bf16x8 (&bsrc)[2][2]) {
        __builtin_amdgcn_s_setprio(1);
#pragma unroll
        for (int st = 0; st < 2; ++st)       // st outermost: 8 independent chains per pass
#pragma unroll
            for (int mi = 0; mi < 4; ++mi)
#pragma unroll
                for (int ni = 0; ni < 2; ++ni)
                    acc[mh][nh][mi][ni] = __builtin_amdgcn_mfma_f32_16x16x32_bf16(
                        afr[mi][st], bsrc[ni][st], acc[mh][nh][mi][ni], 0, 0, 0);
        __builtin_amdgcn_s_setprio(0);
    };

    for (int tp = 0; tp < NP; ++tp) {
        const int u = 2 * tp, v = u + 1;
        const int w = (u + 2 < NT) ? u + 2 : NT - 1;  // tail clamps are region-safe dummies
        const int x = (v + 2 < NT) ? v + 2 : NT - 1;

        // P1: reads u.A0(8)+u.B0(4); stage v.A1 -> s1A1
        RD_A(0, 0); RD_B(bf0, 0, 0);
        stage_half(Ab + 128 * LD + v * BK, &As[1][1][0], wave, lane);
        WAITL8();
        BAR(); WAITL0();
        MFMA_Q(0, 0, bf0);
        BAR();

        // P2: reads u.B1(4); stage w.A0 -> s0A0 (dead after P1)
        RD_B(bf1, 0, 1);
        stage_half(Ab + w * BK, &As[0][0][0], wave, lane);
        BAR(); WAITL0();
        MFMA_Q(0, 1, bf1);
        BAR();

        // P3: reads u.A1(8); stage w.B0 -> s0B0 (dead after P1)
        RD_A(0, 1);
        stage_half(Bb + w * BK, &Bs[0][0][0], wave, lane);
        BAR(); WAITL0();
        MFMA_Q(1, 0, bf0);
        BAR();

        // P4: no reads; stage w.B1 -> s0B1 (dead after P2); vmcnt(6) retires ALL of v
        stage_half(Bb + 128 * LD + w * BK, &Bs[0][1][0], wave, lane);
        WAITV(6);
        BAR();
        MFMA_Q(1, 1, bf1);
        BAR();

        // P5: reads v.A0(8)+v.B0(4); stage w.A1 -> s0A1 (dead after P3)
        RD_A(1, 0); RD_B(bf0, 1, 0);
        stage_half(Ab + 128 * LD + w * BK, &As[0][1][0], wave, lane);
        WAITL8();
        BAR(); WAITL0();
        MFMA_Q(0, 0, bf0);
        BAR();

        // P6: reads v.B1(4); stage x.A0 -> s1A0 (dead after P5)
        RD_B(bf1, 1, 1);
        stage_half(Ab + x * BK, &As[1][0][0], wave, lane);
        BAR(); WAITL0();
        MFMA_Q(0, 1, bf1);
        BAR();

        // P7: reads v.A1(8); stage x.B0 -> s1B0 (dead after P5)
        RD_A(1, 1);
        stage_half(Bb + x * BK, &Bs[1][0][0], wave, lane);
        BAR(); WAITL0();
        MFMA_Q(1, 0, bf0);
        BAR();

        // P8: no reads; stage x.B1 -> s1B1 (dead after P6); vmcnt(6) retires ALL of w
        stage_half(Bb + 128 * LD + x * BK, &Bs[1][1][0], wave, lane);
        WAITV(6);
        BAR();
        MFMA_Q(1, 1, bf1);
        BAR();
    }
    WAITV(0);  // drain tail dummy stages before exit

    // epilogue: row = m0 + mh*128 + wm*64 + mi*16 + ks*4 + j; col = n0 + nh*128 + wn*32 + ni*16 + lr
    const int rsub = ks * 4;
#pragma unroll
    for (int mh = 0; mh < 2; ++mh)
#pragma unroll
        for (int mi = 0; mi < 4; ++mi)
#pragma unroll
            for (int j = 0; j < 4; ++j) {
                const int r = m0 + mh * 128 + wm * 64 + mi * 16 + rsub + j;
                float bv = 0.f;
                if (EPI == 1) bv = bias[r];
#pragma unroll
                for (int nh = 0; nh < 2; ++nh)
#pragma unroll
                    for (int ni = 0; ni < 2; ++ni) {
                        const int c = n0 + nh * 128 + wn * 32 + ni * 16 + lr;
                        const float vv = acc[mh][nh][mi][ni][j] + bv;
                        if (EPI == 0) ((float*)Call)[sC * z + (size_t)r * LD + c] = vv;
                        else          ((bf16_t*)Call)[sC * z + (size_t)r * LD + c] = (bf16_t)vv;
                    }
            }
}

// ---------------- squared row norms of Kb/Qb (bf16 [N,C,B]) -> f32 [N,C] ----------------
__global__ void k_row_norm2(const bf16_t* __restrict__ Kb, const bf16_t* __restrict__ Qb,
                            float* __restrict__ DK2, float* __restrict__ DQ2) {
    const int row = blockIdx.x, n = blockIdx.y;
    const bf16_t* src = blockIdx.z ? Qb : Kb;
    float* dst = blockIdx.z ? DQ2 : DK2;
    const bf16_t* pr = src + ((size_t)n * CD + row) * BD + threadIdx.x * 8;
    bf16x8 v = *(const bf16x8*)pr;
    float s = 0.f;
#pragma unroll
    for (int e = 0; e < 8; ++e) { float x = (float)v[e]; s += x * x; }
#pragma unroll
    for (int off = 32; off; off >>= 1) s += __shfl_xor(s, off, 64);
    __shared__ float ws[4];
    if ((threadIdx.x & 63) == 0) ws[threadIdx.x >> 6] = s;
    __syncthreads();
    if (threadIdx.x == 0) dst[(size_t)n * CD + row] = ws[0] + ws[1] + ws[2] + ws[3];
}

// --- per-row: scale bf16 Yt by rsqrt(DQ2[i]*DK2[j]), softmax over i, write bf16 SMT[j,i] ---
__global__ void k_softmax_rows(const bf16_t* __restrict__ Yt, const float* __restrict__ DK2,
                               const float* __restrict__ DQ2, bf16_t* __restrict__ SMT) {
    const int j = blockIdx.x, n = blockIdx.y, t = threadIdx.x;
    const int lane = t & 63, wave = t >> 6;
    const bf16_t* y = Yt + ((size_t)n * CD + j) * CD;
    const float* q2 = DQ2 + (size_t)n * CD;
    const float dk2 = DK2[(size_t)n * CD + j];
    const int i0 = t * 8;

    bf16x8 yr = *(const bf16x8*)(y + i0);
    float4 qa = *(const float4*)(q2 + i0);
    float4 qb = *(const float4*)(q2 + i0 + 4);
    float qv[8] = {qa.x, qa.y, qa.z, qa.w, qb.x, qb.y, qb.z, qb.w};
    float v[8];
#pragma unroll
    for (int e = 0; e < 8; ++e)
        v[e] = (float)yr[e] * rsqrtf(fmaxf(dk2 * qv[e], 1e-12f));

    float m = v[0];
#pragma unroll
    for (int e = 1; e < 8; ++e) m = fmaxf(m, v[e]);
#pragma unroll
    for (int off = 32; off; off >>= 1) m = fmaxf(m, __shfl_xor(m, off, 64));
    __shared__ float redm[4], reds[4];
    if (lane == 0) redm[wave] = m;
    __syncthreads();
    m = fmaxf(fmaxf(redm[0], redm[1]), fmaxf(redm[2], redm[3]));

    float e8[8];
    float s = 0.f;
#pragma unroll
    for (int e = 0; e < 8; ++e) { e8[e] = __expf(v[e] - m); s += e8[e]; }
#pragma unroll
    for (int off = 32; off; off >>= 1) s += __shfl_xor(s, off, 64);
    if (lane == 0) reds[wave] = s;
    __syncthreads();
    s = reds[0] + reds[1] + reds[2] + reds[3];
    const float inv = 1.f / s;

    bf16x8 o;
#pragma unroll
    for (int e = 0; e < 8; ++e) o[e] = (bf16_t)(e8[e] * inv);
    *(bf16x8*)(SMT + ((size_t)n * CD + j) * CD + i0) = o;
}

extern "C" void kernel_launch(void* const* d_in, const int* in_sizes, int n_in,
                              void* d_out, int out_size, void* d_ws, size_t ws_size,
                              hipStream_t stream) {
    const float* X   = (const float*)d_in[0];
    const float* Wk  = (const float*)d_in[1];
    const float* Wq  = (const float*)d_in[2];
    const float* Wk0 = (const float*)d_in[3];
    const float* Wq0 = (const float*)d_in[4];
    float* Z = (float*)d_out;

    const size_t NCB = (size_t)NB * CD * BD;
    const size_t CC  = (size_t)CD * CD;
    const size_t NCC = (size_t)NB * CC;

    char* p = (char*)d_ws;
    bf16_t* XbT = (bf16_t*)p; p += NCB * 2;
    bf16_t* Wkb = (bf16_t*)p; p += CC * 2;
    bf16_t* Wqb = (bf16_t*)p; p += CC * 2;
    bf16_t* Kb  = (bf16_t*)p; p += NCB * 2;
    bf16_t* Qb  = (bf16_t*)p; p += NCB * 2;
    float*  DK2 = (float*)p;  p += (size_t)NB * CD * 4;
    float*  DQ2 = (float*)p;  p += (size_t)NB * CD * 4;
    bf16_t* Yt  = (bf16_t*)p; p += NCC * 2;   // Yt now bf16 [N,Cj,Ci]
    bf16_t* SMT = Kb;  // Kb dead after Yt; reuse
    if ((size_t)(p - (char*)d_ws) > ws_size) return;

    dim3 blk(256);
    k_transpose_x<<<dim3(BD / 64, CD / 64, NB), blk, 0, stream>>>(X, XbT);
    k_convert_w<<<dim3(CC / 1024, 2), blk, 0, stream>>>(Wk, Wq, Wkb, Wqb);
    k_gemm256<1><<<512, 512, 0, stream>>>(Wkb, 0, XbT, (size_t)BD * CD, Kb, (size_t)CD * BD, Wk0);
    k_gemm256<1><<<512, 512, 0, stream>>>(Wqb, 0, XbT, (size_t)BD * CD, Qb, (size_t)CD * BD, Wq0);
    k_row_norm2<<<dim3(CD, NB, 2), blk, 0, stream>>>(Kb, Qb, DK2, DQ2);
    k_gemm256<2><<<512, 512, 0, stream>>>(Kb, (size_t)CD * BD, Qb, (size_t)CD * BD, Yt, CC, nullptr);
    k_softmax_rows<<<dim3(CD, NB), blk, 0, stream>>>(Yt, DK2, DQ2, SMT);
    k_gemm256<0><<<512, 512, 0, stream>>>(SMT, CC, XbT, (size_t)BD * CD, Z, (size_t)CD * BD, nullptr);
}

// Round 7
// 577.593 us; speedup vs baseline: 1.0510x; 1.0016x over previous
//
#include <hip/hip_runtime.h>
#include <hip/hip_bf16.h>

typedef __bf16 bf16_t;
typedef __bf16 bf16x8 __attribute__((ext_vector_type(8)));
typedef __bf16 bf16x4 __attribute__((ext_vector_type(4)));
typedef float  f32x4  __attribute__((ext_vector_type(4)));

#define NB 8
#define CD 2048
#define BD 2048
#define LD 2048
#define BK 64
#define NT (LD / BK)
#define NP (NT / 2)

#define BAR()     __builtin_amdgcn_s_barrier()
#define WAITV(n)  asm volatile("s_waitcnt vmcnt(" #n ")" ::: "memory")

// ---------------- X [N,C,B] f32 -> XbT [N,B,C] bf16 (transpose + convert) ----------------
__global__ void k_transpose_x(const float* __restrict__ X, bf16_t* __restrict__ XbT) {
    __shared__ bf16_t tile[64][66];
    const int t = threadIdx.x;
    const int b0 = blockIdx.x * 64, c0 = blockIdx.y * 64, n = blockIdx.z;
    const float* Xn = X + (size_t)n * CD * BD;
    bf16_t* Tn = XbT + (size_t)n * BD * CD;
    const int cl = t & 63, rw = t >> 6;
#pragma unroll
    for (int r = 0; r < 16; ++r) {
        int row = r * 4 + rw;
        tile[row][cl] = (bf16_t)Xn[(size_t)(c0 + row) * BD + b0 + cl];
    }
    __syncthreads();
#pragma unroll
    for (int r = 0; r < 16; ++r) {
        int row = r * 4 + rw;
        Tn[(size_t)(b0 + row) * CD + c0 + cl] = tile[cl][row];
    }
}

// ---------------- Wk/Wq f32 -> bf16 ----------------
__global__ void k_convert_w(const float* __restrict__ Wk, const float* __restrict__ Wq,
                            bf16_t* __restrict__ Wkb, bf16_t* __restrict__ Wqb) {
    const size_t i = ((size_t)blockIdx.x * 256 + threadIdx.x) * 4;
    const float* src = blockIdx.y ? Wq : Wk;
    bf16_t* dst = blockIdx.y ? Wqb : Wkb;
    float4 v = *(const float4*)(src + i);
    bf16x4 o;
    o[0] = (bf16_t)v.x; o[1] = (bf16_t)v.y; o[2] = (bf16_t)v.z; o[3] = (bf16_t)v.w;
    *(bf16x4*)(dst + i) = o;
}

// ============ 256x256 NT GEMM — 8-phase, one-phase ds_read read-ahead ============
// C[M,N] = A[M,K](rm) * B[N,K](rm)^T. 8 waves; per phase all waves compute ONE
// 128x128 C-quadrant (wave sub-tile 64x32, 16 MFMA). Phase p issues phase p+1's
// ds_reads BEFORE p's MFMA cluster so LDS delivery overlaps MFMA execution
// (double A-frag buffers afrE/afrO). lgkm waits are compiler-managed (dependency-
// driven, land just before the consuming MFMA). vmcnt(6)+"memory" at P4/P8 only.

__device__ __forceinline__ void gll16(const bf16_t* g, bf16_t* l) {
    __builtin_amdgcn_global_load_lds((const __attribute__((address_space(1))) void*)g,
                                     (__attribute__((address_space(3))) void*)l, 16, 0, 0);
}

__device__ __forceinline__ void stage_half(const bf16_t* gsrc, bf16_t* ldsh, int w, int l) {
    const int rr = l >> 3;
    const int ce = ((l & 7) ^ rr) * 8;  // pre-swizzled source chunk (involution)
#pragma unroll
    for (int i = 0; i < 2; ++i) {
        const bf16_t* g = gsrc + (size_t)(i * 64 + w * 8 + rr) * LD + ce;
        gll16(g, ldsh + i * 4096 + w * 512);
    }
}

__device__ __forceinline__ bf16x8 lds_frag(const bf16_t* hbase, int row16, int lr, int st, int ks, int swz) {
    const int r = row16 + lr;
    const int ce = (st * 32 + ks * 8) ^ swz;
    return *(const bf16x8*)(hbase + r * 64 + ce);
}

template <int EPI>  // 0: f32 store; 1: +bias[row] bf16 store; 2: plain bf16 store
__global__ __launch_bounds__(512, 2) void k_gemm256(const bf16_t* __restrict__ Aall, size_t sA,
                                                    const bf16_t* __restrict__ Ball, size_t sB,
                                                    void* __restrict__ Call, size_t sC,
                                                    const float* __restrict__ bias) {
    __shared__ alignas(16) bf16_t As[2][2][128 * 64];  // [slot][half]
    __shared__ alignas(16) bf16_t Bs[2][2][128 * 64];
    const int tid = threadIdx.x;
    const int lane = tid & 63, wave = tid >> 6;
    const int wm = wave >> 2, wn = wave & 3;
    const int lr = lane & 15, ks = lane >> 4;
    const int swz = (lr & 7) << 3;

    const int bid = blockIdx.x;
    const int lin = (bid & 7) * 64 + (bid >> 3);       // XCD-aware remap (512 % 8 == 0: bijective)
    const int z = lin >> 6, rem = lin & 63, bm = rem >> 3, bn = rem & 7;
    const int m0 = bm * 256, n0 = bn * 256;

    const bf16_t* Ab = Aall + sA * z + (size_t)m0 * LD;
    const bf16_t* Bb = Ball + sB * z + (size_t)n0 * LD;

    // prologue: t0 {A0,B0,A1,B1}; vmcnt(4); t1 {A0,B0,B1}; vmcnt(6)  (t1.A1 staged at P1)
    stage_half(Ab,                 &As[0][0][0], wave, lane);
    stage_half(Bb,                 &Bs[0][0][0], wave, lane);
    stage_half(Ab + 128 * LD,      &As[0][1][0], wave, lane);
    stage_half(Bb + 128 * LD,      &Bs[0][1][0], wave, lane);
    WAITV(4);
    stage_half(Ab + BK,            &As[1][0][0], wave, lane);
    stage_half(Bb + BK,            &Bs[1][0][0], wave, lane);
    stage_half(Bb + 128 * LD + BK, &Bs[1][1][0], wave, lane);
    WAITV(6);
    BAR();

    f32x4 acc[2][2][4][2] = {};       // [mh][nh][mi][ni]
    bf16x8 afrE[4][2], afrO[4][2], bf0[2][2], bf1[2][2];

    auto RD_A = [&](bf16x8 (&dst)[4][2], int slot, int half) {
#pragma unroll
        for (int mi = 0; mi < 4; ++mi)
#pragma unroll
            for (int st = 0; st < 2; ++st)
                dst[mi][st] = lds_frag(&As[slot][half][0], wm * 64 + mi * 16, lr, st, ks, swz);
    };
    auto RD_B = [&](bf16x8 (&dst)[2][2], int slot, int half) {
#pragma unroll
        for (int ni = 0; ni < 2; ++ni)
#pragma unroll
            for (int st = 0; st < 2; ++st)
                dst[ni][st] = lds_frag(&Bs[slot][half][0], wn * 32 + ni * 16, lr, st, ks, swz);
    };
    auto MFMA_Q = [&](int mh, int nh, bf16x8 (&asrc)[4][2], bf16x8 (&bsrc)[2][2]) {
        __builtin_amdgcn_s_setprio(1);
#pragma unroll
        for (int st = 0; st < 2; ++st)       // st outermost: 8 independent chains per pass
#pragma unroll
            for (int mi = 0; mi < 4; ++mi)
#pragma unroll
                for (int ni = 0; ni < 2; ++ni)
                    acc[mh][nh][mi][ni] = __builtin_amdgcn_mfma_f32_16x16x32_bf16(
                        asrc[mi][st], bsrc[ni][st], acc[mh][nh][mi][ni], 0, 0, 0);
        __builtin_amdgcn_s_setprio(0);
    };

    // pre-loop reads: t0.A0 -> afrE, t0.B0 -> bf0 (feed P1's MFMA)
    RD_A(afrE, 0, 0); RD_B(bf0, 0, 0);

    for (int tp = 0; tp < NP; ++tp) {
        const int u = 2 * tp, v = u + 1;
        const int w = (u + 2 < NT) ? u + 2 : NT - 1;  // tail clamps are region-safe dummies
        const int x = (v + 2 < NT) ? v + 2 : NT - 1;

        // P1: RD u.B1->bf1 (for P2); stage v.A1 -> s1A1; MFMA u Q(0,0)
        RD_B(bf1, 0, 1);
        stage_half(Ab + 128 * LD + v * BK, &As[1][1][0], wave, lane);
        BAR();
        MFMA_Q(0, 0, afrE, bf0);
        BAR();

        // P2: RD u.A1->afrO (for P3); stage w.A0 -> s0A0 (dead after P1); MFMA u Q(0,1)
        RD_A(afrO, 0, 1);
        stage_half(Ab + w * BK, &As[0][0][0], wave, lane);
        BAR();
        MFMA_Q(0, 1, afrE, bf1);
        BAR();

        // P3: no reads; stage w.B0 -> s0B0 (dead after P1); MFMA u Q(1,0)
        stage_half(Bb + w * BK, &Bs[0][0][0], wave, lane);
        BAR();
        MFMA_Q(1, 0, afrO, bf0);
        BAR();

        // P4: stage w.B1 -> s0B1 (dead after P2); vmcnt(6) retires ALL of v; then
        //     RD v.A0->afrE + v.B0->bf0 (for P5) overlapping MFMA u Q(1,1)
        stage_half(Bb + 128 * LD + w * BK, &Bs[0][1][0], wave, lane);
        WAITV(6);
        BAR();
        RD_A(afrE, 1, 0); RD_B(bf0, 1, 0);
        MFMA_Q(1, 1, afrO, bf1);
        BAR();

        // P5: RD v.B1->bf1 (for P6); stage w.A1 -> s0A1 (dead after P3); MFMA v Q(0,0)
        RD_B(bf1, 1, 1);
        stage_half(Ab + 128 * LD + w * BK, &As[0][1][0], wave, lane);
        BAR();
        MFMA_Q(0, 0, afrE, bf0);
        BAR();

        // P6: RD v.A1->afrO (for P7); stage x.A0 -> s1A0 (dead after P5); MFMA v Q(0,1)
        RD_A(afrO, 1, 1);
        stage_half(Ab + x * BK, &As[1][0][0], wave, lane);
        BAR();
        MFMA_Q(0, 1, afrE, bf1);
        BAR();

        // P7: no reads; stage x.B0 -> s1B0 (dead after P5); MFMA v Q(1,0)
        stage_half(Bb + x * BK, &Bs[1][0][0], wave, lane);
        BAR();
        MFMA_Q(1, 0, afrO, bf0);
        BAR();

        // P8: stage x.B1 -> s1B1 (dead after P6); vmcnt(6) retires ALL of w; then
        //     RD w.A0->afrE + w.B0->bf0 (for next P1) overlapping MFMA v Q(1,1)
        stage_half(Bb + 128 * LD + x * BK, &Bs[1][1][0], wave, lane);
        WAITV(6);
        BAR();
        RD_A(afrE, 0, 0); RD_B(bf0, 0, 0);
        MFMA_Q(1, 1, afrO, bf1);
        BAR();
    }
    WAITV(0);  // drain tail dummy stages before exit

    // epilogue: row = m0 + mh*128 + wm*64 + mi*16 + ks*4 + j; col = n0 + nh*128 + wn*32 + ni*16 + lr
    const int rsub = ks * 4;
#pragma unroll
    for (int mh = 0; mh < 2; ++mh)
#pragma unroll
        for (int mi = 0; mi < 4; ++mi)
#pragma unroll
            for (int j = 0; j < 4; ++j) {
                const int r = m0 + mh * 128 + wm * 64 + mi * 16 + rsub + j;
                float bv = 0.f;
                if (EPI == 1) bv = bias[r];
#pragma unroll
                for (int nh = 0; nh < 2; ++nh)
#pragma unroll
                    for (int ni = 0; ni < 2; ++ni) {
                        const int c = n0 + nh * 128 + wn * 32 + ni * 16 + lr;
                        const float vv = acc[mh][nh][mi][ni][j] + bv;
                        if (EPI == 0) ((float*)Call)[sC * z + (size_t)r * LD + c] = vv;
                        else          ((bf16_t*)Call)[sC * z + (size_t)r * LD + c] = (bf16_t)vv;
                    }
            }
}

// ---------------- squared row norms of Kb/Qb (bf16 [N,C,B]) -> f32 [N,C] ----------------
__global__ void k_row_norm2(const bf16_t* __restrict__ Kb, const bf16_t* __restrict__ Qb,
                            float* __restrict__ DK2, float* __restrict__ DQ2) {
    const int row = blockIdx.x, n = blockIdx.y;
    const bf16_t* src = blockIdx.z ? Qb : Kb;
    float* dst = blockIdx.z ? DQ2 : DK2;
    const bf16_t* pr = src + ((size_t)n * CD + row) * BD + threadIdx.x * 8;
    bf16x8 v = *(const bf16x8*)pr;
    float s = 0.f;
#pragma unroll
    for (int e = 0; e < 8; ++e) { float x = (float)v[e]; s += x * x; }
#pragma unroll
    for (int off = 32; off; off >>= 1) s += __shfl_xor(s, off, 64);
    __shared__ float ws[4];
    if ((threadIdx.x & 63) == 0) ws[threadIdx.x >> 6] = s;
    __syncthreads();
    if (threadIdx.x == 0) dst[(size_t)n * CD + row] = ws[0] + ws[1] + ws[2] + ws[3];
}

// --- per-row: scale bf16 Yt by rsqrt(DQ2[i]*DK2[j]), softmax over i, write bf16 SMT[j,i] ---
__global__ void k_softmax_rows(const bf16_t* __restrict__ Yt, const float* __restrict__ DK2,
                               const float* __restrict__ DQ2, bf16_t* __restrict__ SMT) {
    const int j = blockIdx.x, n = blockIdx.y, t = threadIdx.x;
    const int lane = t & 63, wave = t >> 6;
    const bf16_t* y = Yt + ((size_t)n * CD + j) * CD;
    const float* q2 = DQ2 + (size_t)n * CD;
    const float dk2 = DK2[(size_t)n * CD + j];
    const int i0 = t * 8;

    bf16x8 yr = *(const bf16x8*)(y + i0);
    float4 qa = *(const float4*)(q2 + i0);
    float4 qb = *(const float4*)(q2 + i0 + 4);
    float qv[8] = {qa.x, qa.y, qa.z, qa.w, qb.x, qb.y, qb.z, qb.w};
    float v[8];
#pragma unroll
    for (int e = 0; e < 8; ++e)
        v[e] = (float)yr[e] * rsqrtf(fmaxf(dk2 * qv[e], 1e-12f));

    float m = v[0];
#pragma unroll
    for (int e = 1; e < 8; ++e) m = fmaxf(m, v[e]);
#pragma unroll
    for (int off = 32; off; off >>= 1) m = fmaxf(m, __shfl_xor(m, off, 64));
    __shared__ float redm[4], reds[4];
    if (lane == 0) redm[wave] = m;
    __syncthreads();
    m = fmaxf(fmaxf(redm[0], redm[1]), fmaxf(redm[2], redm[3]));

    float e8[8];
    float s = 0.f;
#pragma unroll
    for (int e = 0; e < 8; ++e) { e8[e] = __expf(v[e] - m); s += e8[e]; }
#pragma unroll
    for (int off = 32; off; off >>= 1) s += __shfl_xor(s, off, 64);
    if (lane == 0) reds[wave] = s;
    __syncthreads();
    s = reds[0] + reds[1] + reds[2] + reds[3];
    const float inv = 1.f / s;

    bf16x8 o;
#pragma unroll
    for (int e = 0; e < 8; ++e) o[e] = (bf16_t)(e8[e] * inv);
    *(bf16x8*)(SMT + ((size_t)n * CD + j) * CD + i0) = o;
}

extern "C" void kernel_launch(void* const* d_in, const int* in_sizes, int n_in,
                              void* d_out, int out_size, void* d_ws, size_t ws_size,
                              hipStream_t stream) {
    const float* X   = (const float*)d_in[0];
    const float* Wk  = (const float*)d_in[1];
    const float* Wq  = (const float*)d_in[2];
    const float* Wk0 = (const float*)d_in[3];
    const float* Wq0 = (const float*)d_in[4];
    float* Z = (float*)d_out;

    const size_t NCB = (size_t)NB * CD * BD;
    const size_t CC  = (size_t)CD * CD;
    const size_t NCC = (size_t)NB * CC;

    char* p = (char*)d_ws;
    bf16_t* XbT = (bf16_t*)p; p += NCB * 2;
    bf16_t* Wkb = (bf16_t*)p; p += CC * 2;
    bf16_t* Wqb = (bf16_t*)p; p += CC * 2;
    bf16_t* Kb  = (bf16_t*)p; p += NCB * 2;
    bf16_t* Qb  = (bf16_t*)p; p += NCB * 2;
    float*  DK2 = (float*)p;  p += (size_t)NB * CD * 4;
    float*  DQ2 = (float*)p;  p += (size_t)NB * CD * 4;
    bf16_t* Yt  = (bf16_t*)p; p += NCC * 2;   // Yt bf16 [N,Cj,Ci]
    bf16_t* SMT = Kb;  // Kb dead after Yt; reuse
    if ((size_t)(p - (char*)d_ws) > ws_size) return;

    dim3 blk(256);
    k_transpose_x<<<dim3(BD / 64, CD / 64, NB), blk, 0, stream>>>(X, XbT);
    k_convert_w<<<dim3(CC / 1024, 2), blk, 0, stream>>>(Wk, Wq, Wkb, Wqb);
    k_gemm256<1><<<512, 512, 0, stream>>>(Wkb, 0, XbT, (size_t)BD * CD, Kb, (size_t)CD * BD, Wk0);
    k_gemm256<1><<<512, 512, 0, stream>>>(Wqb, 0, XbT, (size_t)BD * CD, Qb, (size_t)CD * BD, Wq0);
    k_row_norm2<<<dim3(CD, NB, 2), blk, 0, stream>>>(Kb, Qb, DK2, DQ2);
    k_gemm256<2><<<512, 512, 0, stream>>>(Kb, (size_t)CD * BD, Qb, (size_t)CD * BD, Yt, CC, nullptr);
    k_softmax_rows<<<dim3(CD, NB), blk, 0, stream>>>(Yt, DK2, DQ2, SMT);
    k_gemm256<0><<<512, 512, 0, stream>>>(SMT, CC, XbT, (size_t)BD * CD, Z, (size_t)CD * BD, nullptr);
}

// Round 9
// 558.921 us; speedup vs baseline: 1.0861x; 1.0334x over previous
//
#include <hip/hip_runtime.h>
#include <hip/hip_bf16.h>

typedef __bf16 bf16_t;
typedef __bf16 bf16x8 __attribute__((ext_vector_type(8)));
typedef __bf16 bf16x4 __attribute__((ext_vector_type(4)));
typedef float  f32x4  __attribute__((ext_vector_type(4)));

#define NB 8
#define CD 2048
#define BD 2048
#define LD 2048
#define BK 64
#define NT (LD / BK)
#define NP (NT / 2)

#define BAR()     __builtin_amdgcn_s_barrier()
#define WAITV(n)  asm volatile("s_waitcnt vmcnt(" #n ")" ::: "memory")
#define M_DSRD 0x100
#define M_MFMA 0x008

// interleave directive: {DS_READ NRD, MFMA 4} x4 — args must be literal constants
template <int NRD>
__device__ __forceinline__ void ilv_pattern() {
#pragma unroll
    for (int g = 0; g < 4; ++g) {
        __builtin_amdgcn_sched_group_barrier(M_DSRD, NRD, 0);
        __builtin_amdgcn_sched_group_barrier(M_MFMA, 4, 0);
    }
}

// ---------------- X [N,C,B] f32 -> XbT [N,B,C] bf16 (transpose + convert) ----------------
__global__ void k_transpose_x(const float* __restrict__ X, bf16_t* __restrict__ XbT) {
    __shared__ bf16_t tile[64][66];
    const int t = threadIdx.x;
    const int b0 = blockIdx.x * 64, c0 = blockIdx.y * 64, n = blockIdx.z;
    const float* Xn = X + (size_t)n * CD * BD;
    bf16_t* Tn = XbT + (size_t)n * BD * CD;
    const int cl = t & 63, rw = t >> 6;
#pragma unroll
    for (int r = 0; r < 16; ++r) {
        int row = r * 4 + rw;
        tile[row][cl] = (bf16_t)Xn[(size_t)(c0 + row) * BD + b0 + cl];
    }
    __syncthreads();
#pragma unroll
    for (int r = 0; r < 16; ++r) {
        int row = r * 4 + rw;
        Tn[(size_t)(b0 + row) * CD + c0 + cl] = tile[cl][row];
    }
}

// ---------------- Wk/Wq f32 -> bf16 ----------------
__global__ void k_convert_w(const float* __restrict__ Wk, const float* __restrict__ Wq,
                            bf16_t* __restrict__ Wkb, bf16_t* __restrict__ Wqb) {
    const size_t i = ((size_t)blockIdx.x * 256 + threadIdx.x) * 4;
    const float* src = blockIdx.y ? Wq : Wk;
    bf16_t* dst = blockIdx.y ? Wqb : Wkb;
    float4 v = *(const float4*)(src + i);
    bf16x4 o;
    o[0] = (bf16_t)v.x; o[1] = (bf16_t)v.y; o[2] = (bf16_t)v.z; o[3] = (bf16_t)v.w;
    *(bf16x4*)(dst + i) = o;
}

// ============ 256x256 NT GEMM — 8-phase, SGB-interleaved reads under MFMA ============
// C[M,N] = A[M,K](rm) * B[N,K](rm)^T. 8 waves; per phase all waves compute ONE
// 128x128 C-quadrant (wave 64x32 piece, 16 MFMA). Next phase's ds_reads are issued
// in the SAME scheduling region as this phase's MFMA cluster, with
// sched_group_barrier forcing {DS_READ n, MFMA 4}x4 interleave so the LDS pipe
// (2635 cyc/K-tile floor) drains UNDER the MFMA pipe (2483 cyc/K-tile) instead of
// serializing with it. vmcnt(6)+"memory" at P4/P8 only; lgkm waits compiler-managed.

__device__ __forceinline__ void gll16(const bf16_t* g, bf16_t* l) {
    __builtin_amdgcn_global_load_lds((const __attribute__((address_space(1))) void*)g,
                                     (__attribute__((address_space(3))) void*)l, 16, 0, 0);
}

__device__ __forceinline__ void stage_half(const bf16_t* gsrc, bf16_t* ldsh, int w, int l) {
    const int rr = l >> 3;
    const int ce = ((l & 7) ^ rr) * 8;  // pre-swizzled source chunk (involution)
#pragma unroll
    for (int i = 0; i < 2; ++i) {
        const bf16_t* g = gsrc + (size_t)(i * 64 + w * 8 + rr) * LD + ce;
        gll16(g, ldsh + i * 4096 + w * 512);
    }
}

__device__ __forceinline__ bf16x8 lds_frag(const bf16_t* hbase, int row16, int lr, int st, int ks, int swz) {
    const int r = row16 + lr;
    const int ce = (st * 32 + ks * 8) ^ swz;
    return *(const bf16x8*)(hbase + r * 64 + ce);
}

template <int EPI>  // 0: f32 store; 1: +bias[row] bf16 store; 2: plain bf16 store
__global__ __launch_bounds__(512, 2) void k_gemm256(const bf16_t* __restrict__ Aall, size_t sA,
                                                    const bf16_t* __restrict__ Ball, size_t sB,
                                                    void* __restrict__ Call, size_t sC,
                                                    const float* __restrict__ bias) {
    __shared__ alignas(16) bf16_t As[2][2][128 * 64];  // [slot][half]
    __shared__ alignas(16) bf16_t Bs[2][2][128 * 64];
    const int tid = threadIdx.x;
    const int lane = tid & 63, wave = tid >> 6;
    const int wm = wave >> 2, wn = wave & 3;
    const int lr = lane & 15, ks = lane >> 4;
    const int swz = (lr & 7) << 3;

    const int bid = blockIdx.x;
    const int lin = (bid & 7) * 64 + (bid >> 3);       // XCD-aware remap (512 % 8 == 0: bijective)
    const int z = lin >> 6, rem = lin & 63, bm = rem >> 3, bn = rem & 7;
    const int m0 = bm * 256, n0 = bn * 256;

    const bf16_t* Ab = Aall + sA * z + (size_t)m0 * LD;
    const bf16_t* Bb = Ball + sB * z + (size_t)n0 * LD;

    // prologue: t0 {A0,B0,A1,B1}; vmcnt(4); t1 {A0,B0,B1}; vmcnt(6)  (t1.A1 staged at P1)
    stage_half(Ab,                 &As[0][0][0], wave, lane);
    stage_half(Bb,                 &Bs[0][0][0], wave, lane);
    stage_half(Ab + 128 * LD,      &As[0][1][0], wave, lane);
    stage_half(Bb + 128 * LD,      &Bs[0][1][0], wave, lane);
    WAITV(4);
    stage_half(Ab + BK,            &As[1][0][0], wave, lane);
    stage_half(Bb + BK,            &Bs[1][0][0], wave, lane);
    stage_half(Bb + 128 * LD + BK, &Bs[1][1][0], wave, lane);
    WAITV(6);
    BAR();

    f32x4 acc[2][2][4][2] = {};       // [mh][nh][mi][ni]
    bf16x8 afrE[4][2], afrO[4][2], bf0[2][2], bf1[2][2];

    auto RD_A = [&](bf16x8 (&dst)[4][2], int slot, int half) {
#pragma unroll
        for (int mi = 0; mi < 4; ++mi)
#pragma unroll
            for (int st = 0; st < 2; ++st)
                dst[mi][st] = lds_frag(&As[slot][half][0], wm * 64 + mi * 16, lr, st, ks, swz);
    };
    auto RD_B = [&](bf16x8 (&dst)[2][2], int slot, int half) {
#pragma unroll
        for (int ni = 0; ni < 2; ++ni)
#pragma unroll
            for (int st = 0; st < 2; ++st)
                dst[ni][st] = lds_frag(&Bs[slot][half][0], wn * 32 + ni * 16, lr, st, ks, swz);
    };
    auto MFMA_Q = [&](int mh, int nh, bf16x8 (&asrc)[4][2], bf16x8 (&bsrc)[2][2]) {
#pragma unroll
        for (int st = 0; st < 2; ++st)       // st outermost: 8 independent chains per pass
#pragma unroll
            for (int mi = 0; mi < 4; ++mi)
#pragma unroll
                for (int ni = 0; ni < 2; ++ni)
                    acc[mh][nh][mi][ni] = __builtin_amdgcn_mfma_f32_16x16x32_bf16(
                        asrc[mi][st], bsrc[ni][st], acc[mh][nh][mi][ni], 0, 0, 0);
    };

    // pre-loop reads: t0.A0 -> afrE, t0.B0 -> bf0 (feed P1's MFMA)
    RD_A(afrE, 0, 0); RD_B(bf0, 0, 0);

    for (int tp = 0; tp < NP; ++tp) {
        const int u = 2 * tp, v = u + 1;
        const int w = (u + 2 < NT) ? u + 2 : NT - 1;  // tail clamps are region-safe dummies
        const int x = (v + 2 < NT) ? v + 2 : NT - 1;

        // P1: stage v.A1 -> s1A1 | RD u.B1->bf1 (4) interleaved with MFMA u Q(0,0)
        stage_half(Ab + 128 * LD + v * BK, &As[1][1][0], wave, lane);
        BAR();
        __builtin_amdgcn_s_setprio(1);
        RD_B(bf1, 0, 1);
        MFMA_Q(0, 0, afrE, bf0);
        ilv_pattern<1>();
        __builtin_amdgcn_s_setprio(0);
        BAR();

        // P2: stage w.A0 -> s0A0 (dead after P1) | RD u.A1->afrO (8) ilv MFMA u Q(0,1)
        stage_half(Ab + w * BK, &As[0][0][0], wave, lane);
        BAR();
        __builtin_amdgcn_s_setprio(1);
        RD_A(afrO, 0, 1);
        MFMA_Q(0, 1, afrE, bf1);
        ilv_pattern<2>();
        __builtin_amdgcn_s_setprio(0);
        BAR();

        // P3: stage w.B0 -> s0B0 (dead after P1) | MFMA u Q(1,0), no reads
        stage_half(Bb + w * BK, &Bs[0][0][0], wave, lane);
        BAR();
        __builtin_amdgcn_s_setprio(1);
        MFMA_Q(1, 0, afrO, bf0);
        __builtin_amdgcn_s_setprio(0);
        BAR();

        // P4: stage w.B1 -> s0B1 (dead after P2); vmcnt(6) retires ALL of v;
        //     RD v.A0->afrE + v.B0->bf0 (12) ilv MFMA u Q(1,1)
        stage_half(Bb + 128 * LD + w * BK, &Bs[0][1][0], wave, lane);
        WAITV(6);
        BAR();
        __builtin_amdgcn_s_setprio(1);
        RD_A(afrE, 1, 0); RD_B(bf0, 1, 0);
        MFMA_Q(1, 1, afrO, bf1);
        ilv_pattern<3>();
        __builtin_amdgcn_s_setprio(0);
        BAR();

        // P5: stage w.A1 -> s0A1 (dead after P3) | RD v.B1->bf1 (4) ilv MFMA v Q(0,0)
        stage_half(Ab + 128 * LD + w * BK, &As[0][1][0], wave, lane);
        BAR();
        __builtin_amdgcn_s_setprio(1);
        RD_B(bf1, 1, 1);
        MFMA_Q(0, 0, afrE, bf0);
        ilv_pattern<1>();
        __builtin_amdgcn_s_setprio(0);
        BAR();

        // P6: stage x.A0 -> s1A0 (dead after P5) | RD v.A1->afrO (8) ilv MFMA v Q(0,1)
        stage_half(Ab + x * BK, &As[1][0][0], wave, lane);
        BAR();
        __builtin_amdgcn_s_setprio(1);
        RD_A(afrO, 1, 1);
        MFMA_Q(0, 1, afrE, bf1);
        ilv_pattern<2>();
        __builtin_amdgcn_s_setprio(0);
        BAR();

        // P7: stage x.B0 -> s1B0 (dead after P5) | MFMA v Q(1,0), no reads
        stage_half(Bb + x * BK, &Bs[1][0][0], wave, lane);
        BAR();
        __builtin_amdgcn_s_setprio(1);
        MFMA_Q(1, 0, afrO, bf0);
        __builtin_amdgcn_s_setprio(0);
        BAR();

        // P8: stage x.B1 -> s1B1 (dead after P6); vmcnt(6) retires ALL of w;
        //     RD w.A0->afrE + w.B0->bf0 (12) ilv MFMA v Q(1,1)
        stage_half(Bb + 128 * LD + x * BK, &Bs[1][1][0], wave, lane);
        WAITV(6);
        BAR();
        __builtin_amdgcn_s_setprio(1);
        RD_A(afrE, 0, 0); RD_B(bf0, 0, 0);
        MFMA_Q(1, 1, afrO, bf1);
        ilv_pattern<3>();
        __builtin_amdgcn_s_setprio(0);
        BAR();
    }
    WAITV(0);  // drain tail dummy stages before exit

    // epilogue: row = m0 + mh*128 + wm*64 + mi*16 + ks*4 + j; col = n0 + nh*128 + wn*32 + ni*16 + lr
    const int rsub = ks * 4;
#pragma unroll
    for (int mh = 0; mh < 2; ++mh)
#pragma unroll
        for (int mi = 0; mi < 4; ++mi)
#pragma unroll
            for (int j = 0; j < 4; ++j) {
                const int r = m0 + mh * 128 + wm * 64 + mi * 16 + rsub + j;
                float bv = 0.f;
                if (EPI == 1) bv = bias[r];
#pragma unroll
                for (int nh = 0; nh < 2; ++nh)
#pragma unroll
                    for (int ni = 0; ni < 2; ++ni) {
                        const int c = n0 + nh * 128 + wn * 32 + ni * 16 + lr;
                        const float vv = acc[mh][nh][mi][ni][j] + bv;
                        if (EPI == 0) ((float*)Call)[sC * z + (size_t)r * LD + c] = vv;
                        else          ((bf16_t*)Call)[sC * z + (size_t)r * LD + c] = (bf16_t)vv;
                    }
            }
}

// ---------------- squared row norms of Kb/Qb (bf16 [N,C,B]) -> f32 [N,C] ----------------
__global__ void k_row_norm2(const bf16_t* __restrict__ Kb, const bf16_t* __restrict__ Qb,
                            float* __restrict__ DK2, float* __restrict__ DQ2) {
    const int row = blockIdx.x, n = blockIdx.y;
    const bf16_t* src = blockIdx.z ? Qb : Kb;
    float* dst = blockIdx.z ? DQ2 : DK2;
    const bf16_t* pr = src + ((size_t)n * CD + row) * BD + threadIdx.x * 8;
    bf16x8 v = *(const bf16x8*)pr;
    float s = 0.f;
#pragma unroll
    for (int e = 0; e < 8; ++e) { float x = (float)v[e]; s += x * x; }
#pragma unroll
    for (int off = 32; off; off >>= 1) s += __shfl_xor(s, off, 64);
    __shared__ float ws[4];
    if ((threadIdx.x & 63) == 0) ws[threadIdx.x >> 6] = s;
    __syncthreads();
    if (threadIdx.x == 0) dst[(size_t)n * CD + row] = ws[0] + ws[1] + ws[2] + ws[3];
}

// --- per-row: scale bf16 Yt by rsqrt(DQ2[i]*DK2[j]), softmax over i, write bf16 SMT[j,i] ---
__global__ void k_softmax_rows(const bf16_t* __restrict__ Yt, const float* __restrict__ DK2,
                               const float* __restrict__ DQ2, bf16_t* __restrict__ SMT) {
    const int j = blockIdx.x, n = blockIdx.y, t = threadIdx.x;
    const int lane = t & 63, wave = t >> 6;
    const bf16_t* y = Yt + ((size_t)n * CD + j) * CD;
    const float* q2 = DQ2 + (size_t)n * CD;
    const float dk2 = DK2[(size_t)n * CD + j];
    const int i0 = t * 8;

    bf16x8 yr = *(const bf16x8*)(y + i0);
    float4 qa = *(const float4*)(q2 + i0);
    float4 qb = *(const float4*)(q2 + i0 + 4);
    float qv[8] = {qa.x, qa.y, qa.z, qa.w, qb.x, qb.y, qb.z, qb.w};
    float v[8];
#pragma unroll
    for (int e = 0; e < 8; ++e)
        v[e] = (float)yr[e] * rsqrtf(fmaxf(dk2 * qv[e], 1e-12f));

    float m = v[0];
#pragma unroll
    for (int e = 1; e < 8; ++e) m = fmaxf(m, v[e]);
#pragma unroll
    for (int off = 32; off; off >>= 1) m = fmaxf(m, __shfl_xor(m, off, 64));
    __shared__ float redm[4], reds[4];
    if (lane == 0) redm[wave] = m;
    __syncthreads();
    m = fmaxf(fmaxf(redm[0], redm[1]), fmaxf(redm[2], redm[3]));

    float e8[8];
    float s = 0.f;
#pragma unroll
    for (int e = 0; e < 8; ++e) { e8[e] = __expf(v[e] - m); s += e8[e]; }
#pragma unroll
    for (int off = 32; off; off >>= 1) s += __shfl_xor(s, off, 64);
    if (lane == 0) reds[wave] = s;
    __syncthreads();
    s = reds[0] + reds[1] + reds[2] + reds[3];
    const float inv = 1.f / s;

    bf16x8 o;
#pragma unroll
    for (int e = 0; e < 8; ++e) o[e] = (bf16_t)(e8[e] * inv);
    *(bf16x8*)(SMT + ((size_t)n * CD + j) * CD + i0) = o;
}

extern "C" void kernel_launch(void* const* d_in, const int* in_sizes, int n_in,
                              void* d_out, int out_size, void* d_ws, size_t ws_size,
                              hipStream_t stream) {
    const float* X   = (const float*)d_in[0];
    const float* Wk  = (const float*)d_in[1];
    const float* Wq  = (const float*)d_in[2];
    const float* Wk0 = (const float*)d_in[3];
    const float* Wq0 = (const float*)d_in[4];
    float* Z = (float*)d_out;

    const size_t NCB = (size_t)NB * CD * BD;
    const size_t CC  = (size_t)CD * CD;
    const size_t NCC = (size_t)NB * CC;

    char* p = (char*)d_ws;
    bf16_t* XbT = (bf16_t*)p; p += NCB * 2;
    bf16_t* Wkb = (bf16_t*)p; p += CC * 2;
    bf16_t* Wqb = (bf16_t*)p; p += CC * 2;
    bf16_t* Kb  = (bf16_t*)p; p += NCB * 2;
    bf16_t* Qb  = (bf16_t*)p; p += NCB * 2;
    float*  DK2 = (float*)p;  p += (size_t)NB * CD * 4;
    float*  DQ2 = (float*)p;  p += (size_t)NB * CD * 4;
    bf16_t* Yt  = (bf16_t*)p; p += NCC * 2;   // Yt bf16 [N,Cj,Ci]
    bf16_t* SMT = Kb;  // Kb dead after Yt; reuse
    if ((size_t)(p - (char*)d_ws) > ws_size) return;

    dim3 blk(256);
    k_transpose_x<<<dim3(BD / 64, CD / 64, NB), blk, 0, stream>>>(X, XbT);
    k_convert_w<<<dim3(CC / 1024, 2), blk, 0, stream>>>(Wk, Wq, Wkb, Wqb);
    k_gemm256<1><<<512, 512, 0, stream>>>(Wkb, 0, XbT, (size_t)BD * CD, Kb, (size_t)CD * BD, Wk0);
    k_gemm256<1><<<512, 512, 0, stream>>>(Wqb, 0, XbT, (size_t)BD * CD, Qb, (size_t)CD * BD, Wq0);
    k_row_norm2<<<dim3(CD, NB, 2), blk, 0, stream>>>(Kb, Qb, DK2, DQ2);
    k_gemm256<2><<<512, 512, 0, stream>>>(Kb, (size_t)CD * BD, Qb, (size_t)CD * BD, Yt, CC, nullptr);
    k_softmax_rows<<<dim3(CD, NB), blk, 0, stream>>>(Yt, DK2, DQ2, SMT);
    k_gemm256<0><<<512, 512, 0, stream>>>(SMT, CC, XbT, (size_t)BD * CD, Z, (size_t)CD * BD, nullptr);
}